// Round 10
// baseline (163.926 us; speedup 1.0000x reference)
//
#include <hip/hip_runtime.h>

typedef __bf16 bf16_t;
typedef __bf16 bf16x4 __attribute__((ext_vector_type(4)));
typedef __bf16 bf16x8 __attribute__((ext_vector_type(8)));
typedef float  f32x4  __attribute__((ext_vector_type(4)));

// Problem constants (setup_inputs: b=2, t=8, C=768, h=w=16)
static constexpr int NHEADS = 12, HC = 64, HW = 256, SEQ = 2048;
static constexpr size_t QKV_ONE = (size_t)2 * NHEADS * SEQ * HC;   // 3145728 elems per q/k/v slab
static constexpr size_t NSTRIDE = 768 * 256;                        // 196608

// async global->LDS DMA, 16B/lane (dest = wave-uniform base + lane*16)
__device__ __forceinline__ void gload_lds16(const bf16_t* g, bf16_t* l) {
    __builtin_amdgcn_global_load_lds(
        (const __attribute__((address_space(1))) void*)g,
        (__attribute__((address_space(3))) void*)l, 16, 0, 0);
}

// ---------------------------------------------------------------------------
// prep: blocks 0..3071 = mp_weight rows (wqkv then wproj, proj columns
// permuted to j=head*64+c); blocks 3072..6143 = x fp32->bf16 transpose tiles.
// (unchanged, verified)
// ---------------------------------------------------------------------------
__global__ __launch_bounds__(256) void va_prep(const float* __restrict__ wqkv,
                                               const float* __restrict__ wproj,
                                               const float* __restrict__ x,
                                               bf16_t* __restrict__ wout,
                                               bf16_t* __restrict__ xt) {
    int blk = blockIdx.x;
    if (blk < 3072) {
        int row = blk;
        bool is_proj = (row >= 2304);
        const float* wr = is_proj ? wproj + (size_t)(row - 2304) * 768
                                  : wqkv + (size_t)row * 768;
        float part = 0.f;
        for (int i = threadIdx.x; i < 768; i += 256) { float v = wr[i]; part += v * v; }
#pragma unroll
        for (int off = 32; off > 0; off >>= 1) part += __shfl_down(part, off, 64);
        __shared__ float red[4];
        if ((threadIdx.x & 63) == 0) red[threadIdx.x >> 6] = part;
        __syncthreads();
        if (threadIdx.x == 0) {
            float s = red[0] + red[1] + red[2] + red[3];
            red[0] = 1.0f / (2.7712813e-3f + sqrtf(s));   // EPS*sqrt(768) + ||w||
        }
        __syncthreads();
        float sc = red[0];
        for (int i = threadIdx.x; i < 768; i += 256) {
            int j = is_proj ? ((i % 12) * 64 + i / 12) : i;
            wout[(size_t)row * 768 + j] = (bf16_t)(wr[i] * sc);
        }
    } else {
        int t = blk - 3072;                 // [0, 3072)
        int n  = t & 15;
        int rest = t >> 4;                  // [0,192)
        int p0 = (rest & 7) * 32;
        int c0 = (rest >> 3) * 32;          // [0,24) * 32
        __shared__ float sm[32][33];
        int tx = threadIdx.x & 31, ty = threadIdx.x >> 5;
        const float* xp = x + (size_t)n * NSTRIDE;
#pragma unroll
        for (int i = 0; i < 4; i++)
            sm[ty + i * 8][tx] = xp[(size_t)(c0 + ty + i * 8) * 256 + p0 + tx];
        __syncthreads();
        bf16_t* xo = xt + (size_t)n * NSTRIDE;
#pragma unroll
        for (int i = 0; i < 4; i++)
            xo[(size_t)(p0 + ty + i * 8) * 768 + c0 + tx] = (bf16_t)sm[tx][ty + i * 8];
    }
}

// ---------------------------------------------------------------------------
// QKV GEMM via MFMA, RoPE + q-scale(+log2e) fused. XCD-remapped by n.
// v5-iso: global_load_lds staging, tested IN ISOLATION this round (round-7's
// NaN was attributed to the attn task-pairing, which round 8 falsified
// alone; this DMA mechanism has no independent verdict yet).
// Double-buffered LDS (2x32KB), one barrier per K-step. LDS dest LINEAR +
// wave-uniform (m104); SOURCE pre-swizzled (rule #21): lane reads global
// chunk (lane&7)^(lane>>3) so linear LDS (row,chunk c) holds global chunk
// c^(row&7) — byte-identical layout to the verified write-side XOR, so the
// ds_read side below is untouched from the verified kernel.
// ---------------------------------------------------------------------------
__global__ __launch_bounds__(256, 2) void va_qkv_mfma(const bf16_t* __restrict__ Wb,
                                                      const bf16_t* __restrict__ xt,
                                                      bf16_t* __restrict__ qkvb) {
    int idx = blockIdx.x;                   // [0,576)
    int n  = (idx & 7) + 8 * ((idx >> 3) & 1);
    int rest = idx >> 4;                    // [0,36)
    int p0 = (rest & 1) * 128;
    int m0 = (rest >> 1) * 128;             // [0,18)*128
    int tid = threadIdx.x;
    int lane = tid & 63, w = tid >> 6;
    int lo = lane & 15, hi = lane >> 4;
    int wm = w >> 1, wn = w & 1;
    int lx = lo & 7;                        // read-side swizzle key (= row&7)

    __shared__ bf16_t Asm[2][128 * 64];     // [buf][row][k], 128B rows
    __shared__ bf16_t Bsm[2][128 * 64];

    // DMA staging: each issue covers 8 rows x 8 chunks (64 lanes x 16B).
    // lane: row_in_group = lane>>3, src chunk = (lane&7)^(lane>>3).
    int r8 = lane >> 3;
    int csw = (lane & 7) ^ r8;
    const bf16_t* Ags = Wb + (size_t)(m0 + w * 32 + r8) * 768 + csw * 8;
    const bf16_t* Bgs = xt + (size_t)n * NSTRIDE + (size_t)(p0 + w * 32 + r8) * 768 + csw * 8;

    auto stage = [&](int s, int buf) {
        int k0 = s * 64;
#pragma unroll
        for (int i = 0; i < 4; i++) {
            gload_lds16(Ags + (size_t)i * 8 * 768 + k0, &Asm[buf][(w * 32 + i * 8) * 64]);
            gload_lds16(Bgs + (size_t)i * 8 * 768 + k0, &Bsm[buf][(w * 32 + i * 8) * 64]);
        }
    };

    f32x4 acc[4][4];
#pragma unroll
    for (int mt = 0; mt < 4; mt++)
#pragma unroll
        for (int nt = 0; nt < 4; nt++) acc[mt][nt] = (f32x4){0.f, 0.f, 0.f, 0.f};

    stage(0, 0);
    __syncthreads();                        // compiler drains vmcnt before
                                            // s_barrier: tile 0 is in LDS
    for (int s = 0; s < 12; s++) {
        int buf = s & 1;
        if (s < 11) stage(s + 1, buf ^ 1);  // async into other buffer; drains
                                            // at this iteration's end barrier
#pragma unroll
        for (int kk = 0; kk < 64; kk += 32) {
            int cb = kk >> 3;               // chunk base: 0 or 4
            bf16x8 af[4], bfr[4];
            const char* Ac = (const char*)Asm[buf];
            const char* Bc = (const char*)Bsm[buf];
#pragma unroll
            for (int mt = 0; mt < 4; mt++) {
                int row = wm * 64 + mt * 16 + lo;
                af[mt] = *(const bf16x8*)(Ac + row * 128 + (((cb + hi) ^ lx) << 4));
            }
#pragma unroll
            for (int nt = 0; nt < 4; nt++) {
                int row = wn * 64 + nt * 16 + lo;
                bfr[nt] = *(const bf16x8*)(Bc + row * 128 + (((cb + hi) ^ lx) << 4));
            }
#pragma unroll
            for (int mt = 0; mt < 4; mt++)
#pragma unroll
                for (int nt = 0; nt < 4; nt++)
                    acc[mt][nt] = __builtin_amdgcn_mfma_f32_16x16x32_bf16(af[mt], bfr[nt], acc[mt][nt], 0, 0, 0);
        }
        __syncthreads();                    // next tile landed + readers done
    }

    int head_global = (m0 + wm * 64) >> 6;
    int qkv_idx = head_global / 12;
    int head    = head_global % 12;
    int b = n >> 3, tt = n & 7;
    int bm = b * 12 + head;
    if (qkv_idx < 2) {
        // q pre-scale folds log2e: exp(S/8) computed as 2^(S*0.18033688)
        float qsc = (qkv_idx == 0) ? 0.18033688011f : 1.0f;
        float ttf = (float)tt;
#pragma unroll
        for (int mt = 0; mt < 2; mt++)
#pragma unroll
            for (int r = 0; r < 4; r++) {
                int j = mt * 16 + hi * 4 + r;
                float ang = ttf * __expf(-(float)j * 0.2878231366242557f);
                float cs = __cosf(ang), sn = __sinf(ang);
#pragma unroll
                for (int nt = 0; nt < 4; nt++) {
                    float x1 = acc[mt][nt][r], x2 = acc[mt + 2][nt][r];
                    acc[mt][nt][r]     = (x1 * cs - x2 * sn) * qsc;
                    acc[mt + 2][nt][r] = (x1 * sn + x2 * cs) * qsc;
                }
            }
        bf16_t* dst = qkvb + (size_t)qkv_idx * QKV_ONE + ((size_t)bm * SEQ + (size_t)tt * HW) * HC;
#pragma unroll
        for (int mt = 0; mt < 4; mt++)
#pragma unroll
            for (int nt = 0; nt < 4; nt++)
#pragma unroll
                for (int r = 0; r < 4; r++) {
                    int cc = mt * 16 + hi * 4 + r;
                    int p  = p0 + wn * 64 + nt * 16 + lo;
                    dst[(size_t)p * HC + cc] = (bf16_t)acc[mt][nt][r];
                }
    } else {
        bf16_t* dst = qkvb + 2 * QKV_ONE + (size_t)bm * HC * SEQ + (size_t)tt * HW;
#pragma unroll
        for (int mt = 0; mt < 4; mt++)
#pragma unroll
            for (int nt = 0; nt < 4; nt++)
#pragma unroll
                for (int r = 0; r < 4; r++) {
                    int cc = mt * 16 + hi * 4 + r;
                    int p  = p0 + wn * 64 + nt * 16 + lo;
                    dst[(size_t)cc * SEQ + p] = (bf16_t)acc[mt][nt][r];
                }
    }
}

// ---------------------------------------------------------------------------
// MFMA flash attention v12 (verified): online, block-level kf split, LDS
// combine, split-phase DS overlap, raw v_exp_f32, setprio. UNCHANGED.
// ---------------------------------------------------------------------------
__global__ __launch_bounds__(256, 2) void va_attn(const bf16_t* __restrict__ qkvb,
                                                  bf16_t* __restrict__ yob) {
    int s = blockIdx.x;                     // [0,768), f-descending heavy-first
    int f = 7 - (s / 96);
    int within = s % 96;
    int bm = within % 24;                   // bm%8 == s%8 -> XCD-pinned per bm
    int qs = within / 24;                   // [0,4) 64-query subtile of frame

    int tid = threadIdx.x;
    int w = tid >> 6, lane = tid & 63;      // w = kf-slice of this wave
    int lo = lane & 15, hi = lane >> 4;
    int lx = lo & 7;                        // swizzle key

    const bf16_t* qbase = qkvb + (size_t)bm * SEQ * HC;
    const bf16_t* kbase = qkvb + QKV_ONE + (size_t)bm * SEQ * HC;
    const bf16_t* vbase = qkvb + 2 * QKV_ONE + (size_t)bm * HC * SEQ;

    __shared__ bf16_t PBF[4][64 * 64];      // wave-private P^T / O-partial slabs
    __shared__ float  Lsm[4][64];           // per-wave l vectors
    bf16_t* PBw = PBF[w];

    // Q B-frags: queries f*256 + qs*64 .. +63 (q pre-scaled 0.125*log2e)
    const bf16_t* qrow = qbase + (size_t)(f * 256 + qs * 64 + lo) * HC;
    bf16x8 qf[4][2];
#pragma unroll
    for (int nq = 0; nq < 4; nq++) {
        qf[nq][0] = *(const bf16x8*)(qrow + (size_t)nq * 16 * HC + hi * 8);
        qf[nq][1] = *(const bf16x8*)(qrow + (size_t)nq * 16 * HC + 32 + hi * 8);
    }
    f32x4 o[4][4];
#pragma unroll
    for (int ct = 0; ct < 4; ct++)
#pragma unroll
        for (int nq = 0; nq < 4; nq++) o[ct][nq] = (f32x4){0.f, 0.f, 0.f, 0.f};
    float l4[4] = {0.f, 0.f, 0.f, 0.f};

    int kend = (f + 1) * 256;

    // ---- K prologue: first tile for this wave
    bf16x8 ka[8];
    {
        const bf16_t* kp = kbase + (size_t)(w * 64 + lo) * HC + hi * 8;
#pragma unroll
        for (int mt = 0; mt < 4; mt++) {
            ka[2 * mt]     = *(const bf16x8*)(kp + (size_t)mt * 16 * HC);
            ka[2 * mt + 1] = *(const bf16x8*)(kp + (size_t)mt * 16 * HC + 32);
        }
    }

    for (int kpos = w * 64; kpos < kend; kpos += 256) {
        // ---- V(kpos): issue FIRST — consumed only in PV, hides under S phase
        const bf16_t* vp = vbase + (size_t)(lo) * SEQ + kpos + hi * 8;
        bf16x8 va[8];
#pragma unroll
        for (int ct = 0; ct < 4; ct++) {
            va[2 * ct]     = *(const bf16x8*)(vp + (size_t)ct * 16 * SEQ);
            va[2 * ct + 1] = *(const bf16x8*)(vp + (size_t)ct * 16 * SEQ + 32);
        }
        // ---- S^T (keys 0..31): mt=0,1 -> exp2 -> pack (chunks 0-3)
        __builtin_amdgcn_s_setprio(1);
#pragma unroll
        for (int mt = 0; mt < 2; mt++) {
#pragma unroll
            for (int nq = 0; nq < 4; nq++) {
                f32x4 sacc = (f32x4){0.f, 0.f, 0.f, 0.f};
                sacc = __builtin_amdgcn_mfma_f32_16x16x32_bf16(ka[2 * mt], qf[nq][0], sacc, 0, 0, 0);
                sacc = __builtin_amdgcn_mfma_f32_16x16x32_bf16(ka[2 * mt + 1], qf[nq][1], sacc, 0, 0, 0);
                bf16x4 pk;
#pragma unroll
                for (int r = 0; r < 4; r++) {
                    float p;
                    asm("v_exp_f32 %0, %1" : "=v"(p) : "v"(sacc[r]));  // 2^x
                    l4[nq] += p;
                    pk[r] = (bf16_t)p;
                }
                *(bf16x4*)(PBw + (nq * 16 + lo) * 64 +
                           (((2 * mt + (hi >> 1)) ^ lx) * 8) + (hi & 1) * 4) = pk;
            }
        }
        __builtin_amdgcn_s_setprio(0);
        // ---- pb0 (keys 0-31): only needs mt=0,1 writes; latency hides
        // under the S(mt=2,3) MFMA below (DS in-order per wave).
        bf16x8 pb0[4], pb1[4];
#pragma unroll
        for (int nq = 0; nq < 4; nq++)
            pb0[nq] = *(const bf16x8*)(PBw + (nq * 16 + lo) * 64 + (hi ^ lx) * 8);
        // ---- S^T (keys 32..63): mt=2,3 -> exp2 -> pack (chunks 4-7)
        __builtin_amdgcn_s_setprio(1);
#pragma unroll
        for (int mt = 2; mt < 4; mt++) {
#pragma unroll
            for (int nq = 0; nq < 4; nq++) {
                f32x4 sacc = (f32x4){0.f, 0.f, 0.f, 0.f};
                sacc = __builtin_amdgcn_mfma_f32_16x16x32_bf16(ka[2 * mt], qf[nq][0], sacc, 0, 0, 0);
                sacc = __builtin_amdgcn_mfma_f32_16x16x32_bf16(ka[2 * mt + 1], qf[nq][1], sacc, 0, 0, 0);
                bf16x4 pk;
#pragma unroll
                for (int r = 0; r < 4; r++) {
                    float p;
                    asm("v_exp_f32 %0, %1" : "=v"(p) : "v"(sacc[r]));  // 2^x
                    l4[nq] += p;
                    pk[r] = (bf16_t)p;
                }
                *(bf16x4*)(PBw + (nq * 16 + lo) * 64 +
                           (((2 * mt + (hi >> 1)) ^ lx) * 8) + (hi & 1) * 4) = pk;
            }
        }
        __builtin_amdgcn_s_setprio(0);
        // ---- K(kpos+256) prefetch: ka free now; hides under PV.
        int knext = (kpos + 256 < kend) ? kpos + 256 : kpos;
        bf16x8 kan[8];
        {
            const bf16_t* kp = kbase + (size_t)(knext + lo) * HC + hi * 8;
#pragma unroll
            for (int mt = 0; mt < 4; mt++) {
                kan[2 * mt]     = *(const bf16x8*)(kp + (size_t)mt * 16 * HC);
                kan[2 * mt + 1] = *(const bf16x8*)(kp + (size_t)mt * 16 * HC + 32);
            }
        }
        // ---- pb1 (keys 32-63): latency hides under PV-half-A below
#pragma unroll
        for (int nq = 0; nq < 4; nq++)
            pb1[nq] = *(const bf16x8*)(PBw + (nq * 16 + lo) * 64 + ((4 + hi) ^ lx) * 8);
        // ---- O^T += V^T·P^T : half A (keys 0-31, pb0), then half B (pb1)
        __builtin_amdgcn_s_setprio(1);
#pragma unroll
        for (int ct = 0; ct < 4; ct++)
#pragma unroll
            for (int nq = 0; nq < 4; nq++)
                o[ct][nq] = __builtin_amdgcn_mfma_f32_16x16x32_bf16(va[2 * ct], pb0[nq], o[ct][nq], 0, 0, 0);
#pragma unroll
        for (int ct = 0; ct < 4; ct++)
#pragma unroll
            for (int nq = 0; nq < 4; nq++)
                o[ct][nq] = __builtin_amdgcn_mfma_f32_16x16x32_bf16(va[2 * ct + 1], pb1[nq], o[ct][nq], 0, 0, 0);
        __builtin_amdgcn_s_setprio(0);
        // ---- rotate K buffers
#pragma unroll
        for (int i = 0; i < 8; i++) ka[i] = kan[i];
    }
    // ---- per-wave l reduction (butterfly over hi) + store to LDS
#pragma unroll
    for (int nq = 0; nq < 4; nq++) {
        l4[nq] += __shfl_xor(l4[nq], 16, 64);
        l4[nq] += __shfl_xor(l4[nq], 32, 64);
    }
    if (hi == 0) {
#pragma unroll
        for (int nq = 0; nq < 4; nq++) Lsm[w][nq * 16 + lo] = l4[nq];
    }
    // ---- pack UNNORMALIZED O-partial (bf16) into wave-private slab
#pragma unroll
    for (int ct = 0; ct < 4; ct++)
#pragma unroll
        for (int nq = 0; nq < 4; nq++) {
            bf16x4 ov;
#pragma unroll
            for (int r = 0; r < 4; r++) ov[r] = (bf16_t)o[ct][nq][r];
            *(bf16x4*)(PBw + (nq * 16 + lo) * 64 +
                       (((2 * ct + (hi >> 1)) ^ lx) * 8) + (hi & 1) * 4) = ov;
        }
    __syncthreads();
    // ---- combine 4 slabs + 4 l's in fp32, normalize, store yob
    int head = bm % 12, b = bm / 12;
    bf16_t* yb = yob + (size_t)(b * 8 + f) * NSTRIDE + (size_t)(qs * 64) * 768 + head * 64;
#pragma unroll
    for (int i = 0; i < 2; i++) {
        int c = i * 256 + tid;              // [0,512) chunk: 64 rows x 8 chunks
        int row = c >> 3, j = c & 7;
        int off = row * 64 + ((j ^ (row & 7)) * 8);
        float invl = 1.0f / (Lsm[0][row] + Lsm[1][row] + Lsm[2][row] + Lsm[3][row]);
        bf16x8 p0 = *(const bf16x8*)(PBF[0] + off);
        bf16x8 p1 = *(const bf16x8*)(PBF[1] + off);
        bf16x8 p2 = *(const bf16x8*)(PBF[2] + off);
        bf16x8 p3 = *(const bf16x8*)(PBF[3] + off);
        bf16x8 o8;
#pragma unroll
        for (int r = 0; r < 8; r++)
            o8[r] = (bf16_t)(((float)p0[r] + (float)p1[r] + (float)p2[r] + (float)p3[r]) * invl);
        *(bf16x8*)(yb + (size_t)row * 768 + j * 8) = o8;
    }
}

// ---------------------------------------------------------------------------
// Proj GEMM via MFMA + mp_sum. XCD-remapped by n.
// v5-iso: same global_load_lds mechanism as qkv (A: 2 issues/wave covering
// rows w*16..+15; B: 4 issues covering w*32..+31). Read side / epilogue
// byte-identical to the verified kernel.
// ---------------------------------------------------------------------------
__global__ __launch_bounds__(256, 2) void va_proj_mfma(const bf16_t* __restrict__ Wb,
                                                       const bf16_t* __restrict__ yob,
                                                       const float* __restrict__ x,
                                                       float* __restrict__ out) {
    int idx = blockIdx.x;                   // [0,384)
    int n  = (idx & 7) + 8 * ((idx >> 3) & 1);
    int rest = idx >> 4;                    // [0,24)
    int p0 = (rest & 1) * 128;
    int m0 = (rest >> 1) * 64;              // [0,12)*64
    int tid = threadIdx.x;
    int lane = tid & 63, w = tid >> 6;      // w = column-slice index [0,4)
    int lo = lane & 15, hi = lane >> 4;
    int lx = lo & 7;

    __shared__ bf16_t Asm[2][64 * 64];      // [buf][m][k]
    __shared__ bf16_t Bsm[2][128 * 64];     // [buf][p][k]

    int r8 = lane >> 3;
    int csw = (lane & 7) ^ r8;
    const bf16_t* Ags = Wb + (size_t)(m0 + w * 16 + r8) * 768 + csw * 8;
    const bf16_t* Bgs = yob + (size_t)n * NSTRIDE + (size_t)(p0 + w * 32 + r8) * 768 + csw * 8;

    auto stage = [&](int s, int buf) {
        int k0 = s * 64;
#pragma unroll
        for (int i = 0; i < 2; i++)
            gload_lds16(Ags + (size_t)i * 8 * 768 + k0, &Asm[buf][(w * 16 + i * 8) * 64]);
#pragma unroll
        for (int i = 0; i < 4; i++)
            gload_lds16(Bgs + (size_t)i * 8 * 768 + k0, &Bsm[buf][(w * 32 + i * 8) * 64]);
    };

    f32x4 acc[4][2];
#pragma unroll
    for (int mt = 0; mt < 4; mt++)
#pragma unroll
        for (int nt = 0; nt < 2; nt++) acc[mt][nt] = (f32x4){0.f, 0.f, 0.f, 0.f};

    stage(0, 0);
    __syncthreads();
    for (int s = 0; s < 12; s++) {
        int buf = s & 1;
        if (s < 11) stage(s + 1, buf ^ 1);
#pragma unroll
        for (int kk = 0; kk < 64; kk += 32) {
            int cb = kk >> 3;
            bf16x8 af[4], bfr[2];
            const char* Ac = (const char*)Asm[buf];
            const char* Bc = (const char*)Bsm[buf];
#pragma unroll
            for (int mt = 0; mt < 4; mt++) {
                int row = mt * 16 + lo;
                af[mt] = *(const bf16x8*)(Ac + row * 128 + (((cb + hi) ^ lx) << 4));
            }
#pragma unroll
            for (int nt = 0; nt < 2; nt++) {
                int row = w * 32 + nt * 16 + lo;
                bfr[nt] = *(const bf16x8*)(Bc + row * 128 + (((cb + hi) ^ lx) << 4));
            }
#pragma unroll
            for (int mt = 0; mt < 4; mt++)
#pragma unroll
                for (int nt = 0; nt < 2; nt++)
                    acc[mt][nt] = __builtin_amdgcn_mfma_f32_16x16x32_bf16(af[mt], bfr[nt], acc[mt][nt], 0, 0, 0);
        }
        __syncthreads();
    }

    const float* xn = x + (size_t)n * NSTRIDE;
    float* on = out + (size_t)n * NSTRIDE;
#pragma unroll
    for (int mt = 0; mt < 4; mt++)
#pragma unroll
        for (int nt = 0; nt < 2; nt++)
#pragma unroll
            for (int r = 0; r < 4; r++) {
                int oo = m0 + mt * 16 + hi * 4 + r;
                int p  = p0 + w * 32 + nt * 16 + lo;
                size_t idx2 = (size_t)oo * 256 + p;
                on[idx2] = (xn[idx2] * 0.7f + acc[mt][nt][r] * 0.3f) * 1.3130643f;
            }
}

// ---------------------------------------------------------------------------
extern "C" void kernel_launch(void* const* d_in, const int* in_sizes, int n_in,
                              void* d_out, int out_size, void* d_ws, size_t ws_size,
                              hipStream_t stream) {
    const float* x     = (const float*)d_in[0];
    const float* wqkv  = (const float*)d_in[1];
    const float* wproj = (const float*)d_in[2];
    float* out = (float*)d_out;

    // Workspace layout kept identical to v8 (Opart/lpart slots now unused).
    bf16_t* Opart = (bf16_t*)d_ws;                             // (unused)
    float*  lpart = (float*)(Opart + (size_t)24 * 36 * 16384); // (unused)
    bf16_t* wqkv_nb  = (bf16_t*)(lpart + (size_t)24 * 36 * 256);
    bf16_t* xt       = wqkv_nb + (size_t)3072 * 768;
    bf16_t* qkvb     = xt + NSTRIDE * 16;
    bf16_t* yob      = qkvb + 3 * QKV_ONE;

    va_prep<<<6144, 256, 0, stream>>>(wqkv, wproj, x, wqkv_nb, xt);
    va_qkv_mfma<<<576, 256, 0, stream>>>(wqkv_nb, xt, qkvb);
    va_attn<<<768, 256, 0, stream>>>(qkvb, yob);
    va_proj_mfma<<<384, 256, 0, stream>>>(wqkv_nb + (size_t)2304 * 768, yob, x, out);
}

// Round 11
// 151.365 us; speedup vs baseline: 1.0830x; 1.0830x over previous
//
#include <hip/hip_runtime.h>

typedef __bf16 bf16_t;
typedef __bf16 bf16x4 __attribute__((ext_vector_type(4)));
typedef __bf16 bf16x8 __attribute__((ext_vector_type(8)));
typedef float  f32x4  __attribute__((ext_vector_type(4)));

// Problem constants (setup_inputs: b=2, t=8, C=768, h=w=16)
static constexpr int NHEADS = 12, HC = 64, HW = 256, SEQ = 2048;
static constexpr size_t QKV_ONE = (size_t)2 * NHEADS * SEQ * HC;   // 3145728 elems per q/k/v slab
static constexpr size_t NSTRIDE = 768 * 256;                        // 196608

// ---------------------------------------------------------------------------
// Session ledger (for future sessions):
//   253.2 -> 149.8/152.6 us across rounds 0-9. Verified structure:
//   - qkv/proj: reg-staged LDS GEMM (global->reg->ds_write, XOR swizzle).
//     global_load_lds DMA variant is CORRECT but -11us at this shape
//     (round 10): the per-barrier vmcnt(0) drain of the just-issued
//     next-tile DMA outweighs the saved ds_writes at 12 K-steps. Do not
//     re-apply without a drain-free schedule (counted vmcnt + raw barriers).
//   - attn task-pairing (2 tasks/block, 480 blocks): NaN'd 2/2 on HW
//     (rounds 7-8) despite passing paper audit. Falsified; do not re-apply.
//   - Harness floor: 42us workspace re-poison fill at 80% HBM peak.
// ---------------------------------------------------------------------------

// ---------------------------------------------------------------------------
// prep: blocks 0..3071 = mp_weight rows (wqkv then wproj, proj columns
// permuted to j=head*64+c); blocks 3072..6143 = x fp32->bf16 transpose tiles.
// ---------------------------------------------------------------------------
__global__ __launch_bounds__(256) void va_prep(const float* __restrict__ wqkv,
                                               const float* __restrict__ wproj,
                                               const float* __restrict__ x,
                                               bf16_t* __restrict__ wout,
                                               bf16_t* __restrict__ xt) {
    int blk = blockIdx.x;
    if (blk < 3072) {
        int row = blk;
        bool is_proj = (row >= 2304);
        const float* wr = is_proj ? wproj + (size_t)(row - 2304) * 768
                                  : wqkv + (size_t)row * 768;
        float part = 0.f;
        for (int i = threadIdx.x; i < 768; i += 256) { float v = wr[i]; part += v * v; }
#pragma unroll
        for (int off = 32; off > 0; off >>= 1) part += __shfl_down(part, off, 64);
        __shared__ float red[4];
        if ((threadIdx.x & 63) == 0) red[threadIdx.x >> 6] = part;
        __syncthreads();
        if (threadIdx.x == 0) {
            float s = red[0] + red[1] + red[2] + red[3];
            red[0] = 1.0f / (2.7712813e-3f + sqrtf(s));   // EPS*sqrt(768) + ||w||
        }
        __syncthreads();
        float sc = red[0];
        for (int i = threadIdx.x; i < 768; i += 256) {
            int j = is_proj ? ((i % 12) * 64 + i / 12) : i;
            wout[(size_t)row * 768 + j] = (bf16_t)(wr[i] * sc);
        }
    } else {
        int t = blk - 3072;                 // [0, 3072)
        int n  = t & 15;
        int rest = t >> 4;                  // [0,192)
        int p0 = (rest & 7) * 32;
        int c0 = (rest >> 3) * 32;          // [0,24) * 32
        __shared__ float sm[32][33];
        int tx = threadIdx.x & 31, ty = threadIdx.x >> 5;
        const float* xp = x + (size_t)n * NSTRIDE;
#pragma unroll
        for (int i = 0; i < 4; i++)
            sm[ty + i * 8][tx] = xp[(size_t)(c0 + ty + i * 8) * 256 + p0 + tx];
        __syncthreads();
        bf16_t* xo = xt + (size_t)n * NSTRIDE;
#pragma unroll
        for (int i = 0; i < 4; i++)
            xo[(size_t)(p0 + ty + i * 8) * 768 + c0 + tx] = (bf16_t)sm[tx][ty + i * 8];
    }
}

// ---------------------------------------------------------------------------
// QKV GEMM via MFMA, RoPE + q-scale(+log2e) fused. XCD-remapped by n.
// v4 (verified): reg-staged LDS tiles, chunk^(row&7) swizzle both sides.
// q-scale folds log2e (0.125*1.4426950 = 0.18033688) so attn uses a raw
// v_exp_f32 (2^x). exp(S*0.125) == 2^(S*0.18033688).
// ---------------------------------------------------------------------------
__global__ __launch_bounds__(256, 2) void va_qkv_mfma(const bf16_t* __restrict__ Wb,
                                                      const bf16_t* __restrict__ xt,
                                                      bf16_t* __restrict__ qkvb) {
    int idx = blockIdx.x;                   // [0,576)
    int n  = (idx & 7) + 8 * ((idx >> 3) & 1);
    int rest = idx >> 4;                    // [0,36)
    int p0 = (rest & 1) * 128;
    int m0 = (rest >> 1) * 128;             // [0,18)*128
    int tid = threadIdx.x;
    int lane = tid & 63, w = tid >> 6;
    int lo = lane & 15, hi = lane >> 4;
    int wm = w >> 1, wn = w & 1;
    int lx = lo & 7;                        // read-side swizzle key (= row&7)

    __shared__ bf16_t Asm[128 * 64];        // [row 0..127][k 0..63], 128B rows
    __shared__ bf16_t Bsm[128 * 64];

    // staging: thread t owns rows (t>>3)+32i, 16B chunk c=(t&7); dest chunk
    // is XOR-swizzled by row&7 (invariant under +32).
    int srow = tid >> 3, schunk = tid & 7;
    const bf16_t* Ag = Wb + (size_t)(m0 + srow) * 768 + schunk * 8;
    const bf16_t* Bg = xt + (size_t)n * NSTRIDE + (size_t)(p0 + srow) * 768 + schunk * 8;
    int sdst = srow * 128 + ((schunk ^ (srow & 7)) << 4);

    f32x4 acc[4][4];
#pragma unroll
    for (int mt = 0; mt < 4; mt++)
#pragma unroll
        for (int nt = 0; nt < 4; nt++) acc[mt][nt] = (f32x4){0.f, 0.f, 0.f, 0.f};

    bf16x8 sa[4], sb[4];                    // stage registers (4 rows each of A,B)

    auto gload = [&](int k0) {
#pragma unroll
        for (int i = 0; i < 4; i++) {
            sa[i] = *(const bf16x8*)(Ag + (size_t)i * 32 * 768 + k0);
            sb[i] = *(const bf16x8*)(Bg + (size_t)i * 32 * 768 + k0);
        }
    };
    auto swrite = [&]() {
        char* Ac = (char*)Asm;
        char* Bc = (char*)Bsm;
#pragma unroll
        for (int i = 0; i < 4; i++) {
            *(bf16x8*)(Ac + sdst + i * 32 * 128) = sa[i];
            *(bf16x8*)(Bc + sdst + i * 32 * 128) = sb[i];
        }
    };

    gload(0);
    for (int s = 0; s < 12; s++) {
        __syncthreads();                    // previous tile's ds_reads complete
        swrite();                           // (compiler waits vmcnt for sa/sb)
        if (s < 11) gload((s + 1) * 64);    // issue next tile early; drains
                                            // under this tile's MFMA
        __syncthreads();                    // tile visible
#pragma unroll
        for (int kk = 0; kk < 64; kk += 32) {
            int cb = kk >> 3;               // chunk base: 0 or 4
            bf16x8 af[4], bfr[4];
            const char* Ac = (const char*)Asm;
            const char* Bc = (const char*)Bsm;
#pragma unroll
            for (int mt = 0; mt < 4; mt++) {
                int row = wm * 64 + mt * 16 + lo;
                af[mt] = *(const bf16x8*)(Ac + row * 128 + (((cb + hi) ^ lx) << 4));
            }
#pragma unroll
            for (int nt = 0; nt < 4; nt++) {
                int row = wn * 64 + nt * 16 + lo;
                bfr[nt] = *(const bf16x8*)(Bc + row * 128 + (((cb + hi) ^ lx) << 4));
            }
#pragma unroll
            for (int mt = 0; mt < 4; mt++)
#pragma unroll
                for (int nt = 0; nt < 4; nt++)
                    acc[mt][nt] = __builtin_amdgcn_mfma_f32_16x16x32_bf16(af[mt], bfr[nt], acc[mt][nt], 0, 0, 0);
        }
    }

    int head_global = (m0 + wm * 64) >> 6;
    int qkv_idx = head_global / 12;
    int head    = head_global % 12;
    int b = n >> 3, tt = n & 7;
    int bm = b * 12 + head;
    if (qkv_idx < 2) {
        // q pre-scale folds log2e: exp(S/8) computed as 2^(S*0.18033688)
        float qsc = (qkv_idx == 0) ? 0.18033688011f : 1.0f;
        float ttf = (float)tt;
#pragma unroll
        for (int mt = 0; mt < 2; mt++)
#pragma unroll
            for (int r = 0; r < 4; r++) {
                int j = mt * 16 + hi * 4 + r;
                float ang = ttf * __expf(-(float)j * 0.2878231366242557f);
                float cs = __cosf(ang), sn = __sinf(ang);
#pragma unroll
                for (int nt = 0; nt < 4; nt++) {
                    float x1 = acc[mt][nt][r], x2 = acc[mt + 2][nt][r];
                    acc[mt][nt][r]     = (x1 * cs - x2 * sn) * qsc;
                    acc[mt + 2][nt][r] = (x1 * sn + x2 * cs) * qsc;
                }
            }
        bf16_t* dst = qkvb + (size_t)qkv_idx * QKV_ONE + ((size_t)bm * SEQ + (size_t)tt * HW) * HC;
#pragma unroll
        for (int mt = 0; mt < 4; mt++)
#pragma unroll
            for (int nt = 0; nt < 4; nt++)
#pragma unroll
                for (int r = 0; r < 4; r++) {
                    int cc = mt * 16 + hi * 4 + r;
                    int p  = p0 + wn * 64 + nt * 16 + lo;
                    dst[(size_t)p * HC + cc] = (bf16_t)acc[mt][nt][r];
                }
    } else {
        bf16_t* dst = qkvb + 2 * QKV_ONE + (size_t)bm * HC * SEQ + (size_t)tt * HW;
#pragma unroll
        for (int mt = 0; mt < 4; mt++)
#pragma unroll
            for (int nt = 0; nt < 4; nt++)
#pragma unroll
                for (int r = 0; r < 4; r++) {
                    int cc = mt * 16 + hi * 4 + r;
                    int p  = p0 + wn * 64 + nt * 16 + lo;
                    dst[(size_t)cc * SEQ + p] = (bf16_t)acc[mt][nt][r];
                }
    }
}

// ---------------------------------------------------------------------------
// MFMA flash attention v12 (verified): online, block-level kf split, LDS
// combine, split-phase DS overlap, raw v_exp_f32, setprio. 768 blocks,
// one (bm, f, qs) task per block.
// ---------------------------------------------------------------------------
__global__ __launch_bounds__(256, 2) void va_attn(const bf16_t* __restrict__ qkvb,
                                                  bf16_t* __restrict__ yob) {
    int s = blockIdx.x;                     // [0,768), f-descending heavy-first
    int f = 7 - (s / 96);
    int within = s % 96;
    int bm = within % 24;                   // bm%8 == s%8 -> XCD-pinned per bm
    int qs = within / 24;                   // [0,4) 64-query subtile of frame

    int tid = threadIdx.x;
    int w = tid >> 6, lane = tid & 63;      // w = kf-slice of this wave
    int lo = lane & 15, hi = lane >> 4;
    int lx = lo & 7;                        // swizzle key

    const bf16_t* qbase = qkvb + (size_t)bm * SEQ * HC;
    const bf16_t* kbase = qkvb + QKV_ONE + (size_t)bm * SEQ * HC;
    const bf16_t* vbase = qkvb + 2 * QKV_ONE + (size_t)bm * HC * SEQ;

    __shared__ bf16_t PBF[4][64 * 64];      // wave-private P^T / O-partial slabs
    __shared__ float  Lsm[4][64];           // per-wave l vectors
    bf16_t* PBw = PBF[w];

    // Q B-frags: queries f*256 + qs*64 .. +63 (q pre-scaled 0.125*log2e)
    const bf16_t* qrow = qbase + (size_t)(f * 256 + qs * 64 + lo) * HC;
    bf16x8 qf[4][2];
#pragma unroll
    for (int nq = 0; nq < 4; nq++) {
        qf[nq][0] = *(const bf16x8*)(qrow + (size_t)nq * 16 * HC + hi * 8);
        qf[nq][1] = *(const bf16x8*)(qrow + (size_t)nq * 16 * HC + 32 + hi * 8);
    }
    f32x4 o[4][4];
#pragma unroll
    for (int ct = 0; ct < 4; ct++)
#pragma unroll
        for (int nq = 0; nq < 4; nq++) o[ct][nq] = (f32x4){0.f, 0.f, 0.f, 0.f};
    float l4[4] = {0.f, 0.f, 0.f, 0.f};

    int kend = (f + 1) * 256;

    // ---- K prologue: first tile for this wave
    bf16x8 ka[8];
    {
        const bf16_t* kp = kbase + (size_t)(w * 64 + lo) * HC + hi * 8;
#pragma unroll
        for (int mt = 0; mt < 4; mt++) {
            ka[2 * mt]     = *(const bf16x8*)(kp + (size_t)mt * 16 * HC);
            ka[2 * mt + 1] = *(const bf16x8*)(kp + (size_t)mt * 16 * HC + 32);
        }
    }

    for (int kpos = w * 64; kpos < kend; kpos += 256) {
        // ---- V(kpos): issue FIRST — consumed only in PV, hides under S phase
        const bf16_t* vp = vbase + (size_t)(lo) * SEQ + kpos + hi * 8;
        bf16x8 va[8];
#pragma unroll
        for (int ct = 0; ct < 4; ct++) {
            va[2 * ct]     = *(const bf16x8*)(vp + (size_t)ct * 16 * SEQ);
            va[2 * ct + 1] = *(const bf16x8*)(vp + (size_t)ct * 16 * SEQ + 32);
        }
        // ---- S^T (keys 0..31): mt=0,1 -> exp2 -> pack (chunks 0-3)
        __builtin_amdgcn_s_setprio(1);
#pragma unroll
        for (int mt = 0; mt < 2; mt++) {
#pragma unroll
            for (int nq = 0; nq < 4; nq++) {
                f32x4 sacc = (f32x4){0.f, 0.f, 0.f, 0.f};
                sacc = __builtin_amdgcn_mfma_f32_16x16x32_bf16(ka[2 * mt], qf[nq][0], sacc, 0, 0, 0);
                sacc = __builtin_amdgcn_mfma_f32_16x16x32_bf16(ka[2 * mt + 1], qf[nq][1], sacc, 0, 0, 0);
                bf16x4 pk;
#pragma unroll
                for (int r = 0; r < 4; r++) {
                    float p;
                    asm("v_exp_f32 %0, %1" : "=v"(p) : "v"(sacc[r]));  // 2^x
                    l4[nq] += p;
                    pk[r] = (bf16_t)p;
                }
                *(bf16x4*)(PBw + (nq * 16 + lo) * 64 +
                           (((2 * mt + (hi >> 1)) ^ lx) * 8) + (hi & 1) * 4) = pk;
            }
        }
        __builtin_amdgcn_s_setprio(0);
        // ---- pb0 (keys 0-31): only needs mt=0,1 writes; latency hides
        // under the S(mt=2,3) MFMA below (DS in-order per wave).
        bf16x8 pb0[4], pb1[4];
#pragma unroll
        for (int nq = 0; nq < 4; nq++)
            pb0[nq] = *(const bf16x8*)(PBw + (nq * 16 + lo) * 64 + (hi ^ lx) * 8);
        // ---- S^T (keys 32..63): mt=2,3 -> exp2 -> pack (chunks 4-7)
        __builtin_amdgcn_s_setprio(1);
#pragma unroll
        for (int mt = 2; mt < 4; mt++) {
#pragma unroll
            for (int nq = 0; nq < 4; nq++) {
                f32x4 sacc = (f32x4){0.f, 0.f, 0.f, 0.f};
                sacc = __builtin_amdgcn_mfma_f32_16x16x32_bf16(ka[2 * mt], qf[nq][0], sacc, 0, 0, 0);
                sacc = __builtin_amdgcn_mfma_f32_16x16x32_bf16(ka[2 * mt + 1], qf[nq][1], sacc, 0, 0, 0);
                bf16x4 pk;
#pragma unroll
                for (int r = 0; r < 4; r++) {
                    float p;
                    asm("v_exp_f32 %0, %1" : "=v"(p) : "v"(sacc[r]));  // 2^x
                    l4[nq] += p;
                    pk[r] = (bf16_t)p;
                }
                *(bf16x4*)(PBw + (nq * 16 + lo) * 64 +
                           (((2 * mt + (hi >> 1)) ^ lx) * 8) + (hi & 1) * 4) = pk;
            }
        }
        __builtin_amdgcn_s_setprio(0);
        // ---- K(kpos+256) prefetch: ka free now; hides under PV.
        int knext = (kpos + 256 < kend) ? kpos + 256 : kpos;
        bf16x8 kan[8];
        {
            const bf16_t* kp = kbase + (size_t)(knext + lo) * HC + hi * 8;
#pragma unroll
            for (int mt = 0; mt < 4; mt++) {
                kan[2 * mt]     = *(const bf16x8*)(kp + (size_t)mt * 16 * HC);
                kan[2 * mt + 1] = *(const bf16x8*)(kp + (size_t)mt * 16 * HC + 32);
            }
        }
        // ---- pb1 (keys 32-63): latency hides under PV-half-A below
#pragma unroll
        for (int nq = 0; nq < 4; nq++)
            pb1[nq] = *(const bf16x8*)(PBw + (nq * 16 + lo) * 64 + ((4 + hi) ^ lx) * 8);
        // ---- O^T += V^T·P^T : half A (keys 0-31, pb0), then half B (pb1)
        __builtin_amdgcn_s_setprio(1);
#pragma unroll
        for (int ct = 0; ct < 4; ct++)
#pragma unroll
            for (int nq = 0; nq < 4; nq++)
                o[ct][nq] = __builtin_amdgcn_mfma_f32_16x16x32_bf16(va[2 * ct], pb0[nq], o[ct][nq], 0, 0, 0);
#pragma unroll
        for (int ct = 0; ct < 4; ct++)
#pragma unroll
            for (int nq = 0; nq < 4; nq++)
                o[ct][nq] = __builtin_amdgcn_mfma_f32_16x16x32_bf16(va[2 * ct + 1], pb1[nq], o[ct][nq], 0, 0, 0);
        __builtin_amdgcn_s_setprio(0);
        // ---- rotate K buffers
#pragma unroll
        for (int i = 0; i < 8; i++) ka[i] = kan[i];
    }
    // ---- per-wave l reduction (butterfly over hi) + store to LDS
#pragma unroll
    for (int nq = 0; nq < 4; nq++) {
        l4[nq] += __shfl_xor(l4[nq], 16, 64);
        l4[nq] += __shfl_xor(l4[nq], 32, 64);
    }
    if (hi == 0) {
#pragma unroll
        for (int nq = 0; nq < 4; nq++) Lsm[w][nq * 16 + lo] = l4[nq];
    }
    // ---- pack UNNORMALIZED O-partial (bf16) into wave-private slab
#pragma unroll
    for (int ct = 0; ct < 4; ct++)
#pragma unroll
        for (int nq = 0; nq < 4; nq++) {
            bf16x4 ov;
#pragma unroll
            for (int r = 0; r < 4; r++) ov[r] = (bf16_t)o[ct][nq][r];
            *(bf16x4*)(PBw + (nq * 16 + lo) * 64 +
                       (((2 * ct + (hi >> 1)) ^ lx) * 8) + (hi & 1) * 4) = ov;
        }
    __syncthreads();
    // ---- combine 4 slabs + 4 l's in fp32, normalize, store yob
    int head = bm % 12, b = bm / 12;
    bf16_t* yb = yob + (size_t)(b * 8 + f) * NSTRIDE + (size_t)(qs * 64) * 768 + head * 64;
#pragma unroll
    for (int i = 0; i < 2; i++) {
        int c = i * 256 + tid;              // [0,512) chunk: 64 rows x 8 chunks
        int row = c >> 3, j = c & 7;
        int off = row * 64 + ((j ^ (row & 7)) * 8);
        float invl = 1.0f / (Lsm[0][row] + Lsm[1][row] + Lsm[2][row] + Lsm[3][row]);
        bf16x8 p0 = *(const bf16x8*)(PBF[0] + off);
        bf16x8 p1 = *(const bf16x8*)(PBF[1] + off);
        bf16x8 p2 = *(const bf16x8*)(PBF[2] + off);
        bf16x8 p3 = *(const bf16x8*)(PBF[3] + off);
        bf16x8 o8;
#pragma unroll
        for (int r = 0; r < 8; r++)
            o8[r] = (bf16_t)(((float)p0[r] + (float)p1[r] + (float)p2[r] + (float)p3[r]) * invl);
        *(bf16x8*)(yb + (size_t)row * 768 + j * 8) = o8;
    }
}

// ---------------------------------------------------------------------------
// Proj GEMM via MFMA + mp_sum. XCD-remapped by n.
// v4 (verified): reg-staged LDS tiles, 64x128 tile, BK=64.
// ---------------------------------------------------------------------------
__global__ __launch_bounds__(256, 2) void va_proj_mfma(const bf16_t* __restrict__ Wb,
                                                       const bf16_t* __restrict__ yob,
                                                       const float* __restrict__ x,
                                                       float* __restrict__ out) {
    int idx = blockIdx.x;                   // [0,384)
    int n  = (idx & 7) + 8 * ((idx >> 3) & 1);
    int rest = idx >> 4;                    // [0,24)
    int p0 = (rest & 1) * 128;
    int m0 = (rest >> 1) * 64;              // [0,12)*64
    int tid = threadIdx.x;
    int lane = tid & 63, w = tid >> 6;      // w = column-slice index [0,4)
    int lo = lane & 15, hi = lane >> 4;
    int lx = lo & 7;

    __shared__ bf16_t Asm[64 * 64];         // [m 0..63][k 0..63]
    __shared__ bf16_t Bsm[128 * 64];        // [p 0..127][k 0..63]

    int srow = tid >> 3, schunk = tid & 7;  // srow in [0,32)
    const bf16_t* Ag = Wb + (size_t)(m0 + srow) * 768 + schunk * 8;
    const bf16_t* Bg = yob + (size_t)n * NSTRIDE + (size_t)(p0 + srow) * 768 + schunk * 8;
    int sdst = srow * 128 + ((schunk ^ (srow & 7)) << 4);

    f32x4 acc[4][2];
#pragma unroll
    for (int mt = 0; mt < 4; mt++)
#pragma unroll
        for (int nt = 0; nt < 2; nt++) acc[mt][nt] = (f32x4){0.f, 0.f, 0.f, 0.f};

    bf16x8 sa[2], sb[4];
    auto gload = [&](int k0) {
#pragma unroll
        for (int i = 0; i < 2; i++)
            sa[i] = *(const bf16x8*)(Ag + (size_t)i * 32 * 768 + k0);
#pragma unroll
        for (int i = 0; i < 4; i++)
            sb[i] = *(const bf16x8*)(Bg + (size_t)i * 32 * 768 + k0);
    };
    auto swrite = [&]() {
        char* Ac = (char*)Asm;
        char* Bc = (char*)Bsm;
#pragma unroll
        for (int i = 0; i < 2; i++)
            *(bf16x8*)(Ac + sdst + i * 32 * 128) = sa[i];
#pragma unroll
        for (int i = 0; i < 4; i++)
            *(bf16x8*)(Bc + sdst + i * 32 * 128) = sb[i];
    };

    gload(0);
    for (int s = 0; s < 12; s++) {
        __syncthreads();
        swrite();
        if (s < 11) gload((s + 1) * 64);
        __syncthreads();
#pragma unroll
        for (int kk = 0; kk < 64; kk += 32) {
            int cb = kk >> 3;
            bf16x8 af[4], bfr[2];
            const char* Ac = (const char*)Asm;
            const char* Bc = (const char*)Bsm;
#pragma unroll
            for (int mt = 0; mt < 4; mt++) {
                int row = mt * 16 + lo;
                af[mt] = *(const bf16x8*)(Ac + row * 128 + (((cb + hi) ^ lx) << 4));
            }
#pragma unroll
            for (int nt = 0; nt < 2; nt++) {
                int row = w * 32 + nt * 16 + lo;
                bfr[nt] = *(const bf16x8*)(Bc + row * 128 + (((cb + hi) ^ lx) << 4));
            }
#pragma unroll
            for (int mt = 0; mt < 4; mt++)
#pragma unroll
                for (int nt = 0; nt < 2; nt++)
                    acc[mt][nt] = __builtin_amdgcn_mfma_f32_16x16x32_bf16(af[mt], bfr[nt], acc[mt][nt], 0, 0, 0);
        }
    }

    const float* xn = x + (size_t)n * NSTRIDE;
    float* on = out + (size_t)n * NSTRIDE;
#pragma unroll
    for (int mt = 0; mt < 4; mt++)
#pragma unroll
        for (int nt = 0; nt < 2; nt++)
#pragma unroll
            for (int r = 0; r < 4; r++) {
                int oo = m0 + mt * 16 + hi * 4 + r;
                int p  = p0 + w * 32 + nt * 16 + lo;
                size_t idx2 = (size_t)oo * 256 + p;
                on[idx2] = (xn[idx2] * 0.7f + acc[mt][nt][r] * 0.3f) * 1.3130643f;
            }
}

// ---------------------------------------------------------------------------
extern "C" void kernel_launch(void* const* d_in, const int* in_sizes, int n_in,
                              void* d_out, int out_size, void* d_ws, size_t ws_size,
                              hipStream_t stream) {
    const float* x     = (const float*)d_in[0];
    const float* wqkv  = (const float*)d_in[1];
    const float* wproj = (const float*)d_in[2];
    float* out = (float*)d_out;

    // Workspace layout kept identical to v8 (Opart/lpart slots now unused).
    bf16_t* Opart = (bf16_t*)d_ws;                             // (unused)
    float*  lpart = (float*)(Opart + (size_t)24 * 36 * 16384); // (unused)
    bf16_t* wqkv_nb  = (bf16_t*)(lpart + (size_t)24 * 36 * 256);
    bf16_t* xt       = wqkv_nb + (size_t)3072 * 768;
    bf16_t* qkvb     = xt + NSTRIDE * 16;
    bf16_t* yob      = qkvb + 3 * QKV_ONE;

    va_prep<<<6144, 256, 0, stream>>>(wqkv, wproj, x, wqkv_nb, xt);
    va_qkv_mfma<<<576, 256, 0, stream>>>(wqkv_nb, xt, qkvb);
    va_attn<<<768, 256, 0, stream>>>(qkvb, yob);
    va_proj_mfma<<<192 * 2, 256, 0, stream>>>(wqkv_nb + (size_t)2304 * 768, yob, x, out);
}